// Round 2
// baseline (1682.320 us; speedup 1.0000x reference)
//
#include <hip/hip_runtime.h>
#include <hip/hip_fp16.h>

typedef _Float16 f16;
typedef __attribute__((ext_vector_type(8))) _Float16 f16x8;
typedef __attribute__((ext_vector_type(4))) _Float16 f16x4;
typedef __attribute__((ext_vector_type(4))) float f32x4;

#define D_      512
#define NG_     2048
#define B_      64
#define S_      256
#define C_      16
#define M_      (B_*S_)      // 16384

// ---- workspace layout (bytes) ----
#define OFF_X    0ull
#define SZ_X     ((unsigned long long)M_*D_*2)            // x fp16 [16384][512]
#define OFF_G    (OFF_X + SZ_X)
#define SZ_G     ((unsigned long long)M_*NG_*2)           // G fp16 [16384][2048]
#define OFF_WI   (OFF_G + SZ_G)
#define SZ_WI    ((unsigned long long)NG_*D_*2)           // W_ih fp16
#define OFF_HG   (OFF_WI + SZ_WI)
#define SZ_HG    (2ull*4*16*512*2)                        // h slab, dbl-buf [2][4][16][512] f16
#define OFF_FH   (OFF_HG + SZ_HG)
#define SZ_FH    ((unsigned long long)B_*D_*4)            // final_h f32 [64][512]
#define OFF_FL   (OFF_FH + SZ_FH)
#define SZ_FL    1024ull                                  // flags: 4 clusters x 64 uints
#define WS_NEED  (OFF_FL + SZ_FL)

__device__ __forceinline__ float sigmoidf_(float x) { return 1.f / (1.f + __expf(-x)); }
__device__ __forceinline__ float tanhf_(float x) {
  float a = fabsf(x);
  float e = __expf(-2.f * a);
  float r = (1.f - e) / (1.f + e);
  return copysignf(r, x);
}

// ---------------- K0: zero the flags ----------------
__global__ void k_zero(unsigned* __restrict__ p) { p[threadIdx.x] = 0u; }

// ---------------- K1: embedding gather + sum -> x fp16 ----------------
// grid 16384 blocks x 128 thr; block = one (b,s); thread t covers cols 4t..4t+3
__global__ void k_embed(const int* __restrict__ seqs, const float* __restrict__ table,
                        f16* __restrict__ x) {
  const int m = blockIdx.x;
  const int t = threadIdx.x;
  const int* idx = seqs + (size_t)m * C_;
  float4 acc = {0.f, 0.f, 0.f, 0.f};
  #pragma unroll
  for (int r = 0; r < C_; ++r) {
    int id = idx[r];  // row VOCAB is all-zero in the provided table
    const float4* row = (const float4*)(table + (size_t)id * D_);
    float4 v = row[t];
    acc.x += v.x; acc.y += v.y; acc.z += v.z; acc.w += v.w;
  }
  f16x4 o;
  o[0] = (f16)acc.x; o[1] = (f16)acc.y; o[2] = (f16)acc.z; o[3] = (f16)acc.w;
  *(f16x4*)(x + (size_t)m * D_ + t * 4) = o;
}

// ---------------- K1b: convert W_ih fp32 -> fp16 ----------------
__global__ void k_cvtw(const float* __restrict__ w, f16* __restrict__ o, int n) {
  int i = blockIdx.x * 256 + threadIdx.x;
  if (i < n) o[i] = (f16)w[i];
}

// ---------------- K2: G = x @ W_ih^T  (fp16 MFMA, fp32 accum) ----------------
// grid (256 m-tiles, 32 n-tiles) x 256 thr. Per WG: 64x64 tile; wave w owns m-strip w*16.
__global__ void k_gemm_ih(const f16* __restrict__ x, const f16* __restrict__ wi,
                          f16* __restrict__ G) {
  const int mt = blockIdx.x, nt = blockIdx.y;
  const int wid = threadIdx.x >> 6, lane = threadIdx.x & 63;
  const int lr = lane & 15, lq = lane >> 4;
  const int m0 = mt * 64 + wid * 16;
  const int n0 = nt * 64;

  f32x4 acc[4] = {{0.f,0.f,0.f,0.f},{0.f,0.f,0.f,0.f},{0.f,0.f,0.f,0.f},{0.f,0.f,0.f,0.f}};
  for (int kt = 0; kt < 16; ++kt) {
    const int k0 = kt * 32 + lq * 8;
    const f16x8 a = *(const f16x8*)(x + (size_t)(m0 + lr) * D_ + k0);
    #pragma unroll
    for (int j = 0; j < 4; ++j) {
      const f16x8 b = *(const f16x8*)(wi + (size_t)(n0 + j * 16 + lr) * D_ + k0);
      acc[j] = __builtin_amdgcn_mfma_f32_16x16x32_f16(a, b, acc[j], 0, 0, 0);
    }
  }
  // D mapping: col = lane&15 (n), row = (lane>>4)*4 + reg (m)
  #pragma unroll
  for (int j = 0; j < 4; ++j)
    #pragma unroll
    for (int rr = 0; rr < 4; ++rr) {
      const int m = m0 + lq * 4 + rr;
      const int n = n0 + j * 16 + lr;
      G[(size_t)m * NG_ + n] = (f16)acc[j][rr];
    }
}

// ---------------- K3: LSTM recurrence ----------------
// 64 WGs x 512 thr. cluster = bid&3 (16 WGs, 16 chains); rank r = bid>>2.
// WG owns 128 W_hh rows: gates {i,f,g,o} x h-idx [r*32, r*32+32), as persistent
// VGPR B-fragments. Per step: MFMA (A = h from LDS) -> gate slice -> nonlinearity
// -> h exchanged cluster-wide via agent-scope slab + flag counter.
__global__ __launch_bounds__(512, 1) void k_lstm(
    const float* __restrict__ whh, const f16* __restrict__ G,
    const int* __restrict__ lengths, unsigned* __restrict__ hGu,
    unsigned* __restrict__ flags, float* __restrict__ final_h) {
  const int bid = blockIdx.x;
  const int cl = bid & 3;
  const int r = bid >> 2;
  const int tid = threadIdx.x;
  const int wid = tid >> 6, lane = tid & 63;
  const int lr = lane & 15, lq = lane >> 4;

  __shared__ f16 h_lds[16][520];      // [chain][k], row stride 1040 B
  __shared__ float glds[4][32][20];   // [gate][h-idx in WG][chain], padded
  __shared__ int steps_sh;

  // persistent W_hh B-fragments: wave wid -> gate (wid>>1), half (wid&1)
  const int gi = wid >> 1, jh = wid & 1;
  const int nrow = gi * 512 + r * 32 + jh * 16 + lr;
  f16x8 wfrag[16];
  #pragma unroll
  for (int kt = 0; kt < 16; ++kt) {
    const int k0 = kt * 32 + lq * 8;
    const float* p = whh + (size_t)nrow * D_ + k0;
    f16x8 w;
    #pragma unroll
    for (int e = 0; e < 8; ++e) w[e] = (f16)p[e];
    wfrag[kt] = w;
  }

  for (int i = tid; i < 16 * 520; i += 512) ((f16*)h_lds)[i] = (f16)0.f;

  // epilogue thread mapping: chain ec = tid>>5, h-idx-in-WG ej = tid&31
  const int ec = tid >> 5;
  const int ej = tid & 31;
  const int b_ec = cl * 16 + ec;
  const int len_ec = lengths[b_ec];

  if (tid == 0) {
    int mx = 0;
    for (int c = 0; c < 16; ++c) mx = max(mx, lengths[cl * 16 + c]);
    steps_sh = mx;
  }
  float cstate = 0.f;
  __syncthreads();
  const int steps = steps_sh;

  unsigned* flag = flags + cl * 64;
  const f16* Gbase = G + (size_t)(cl * 16) * S_ * NG_;

  for (int t = 0; t < steps; ++t) {
    // 1. MFMA: gates_partial[chain, n-slice] = h @ W_hh_slice^T
    f32x4 acc = {0.f, 0.f, 0.f, 0.f};
    #pragma unroll
    for (int kt = 0; kt < 16; ++kt) {
      const f16x8 a = *(const f16x8*)&h_lds[lr][kt * 32 + lq * 8];
      acc = __builtin_amdgcn_mfma_f32_16x16x32_f16(a, wfrag[kt], acc, 0, 0, 0);
    }
    // 2. D: row = chain = lq*4+reg, col = lane&15 -> glds[gate][j][chain]
    *(f32x4*)&glds[gi][jh * 16 + lr][lq * 4] = acc;
    __syncthreads();

    // 3. epilogue: thread (ec, ej)
    {
      const f16* gp = Gbase + (size_t)(ec * S_ + t) * NG_ + r * 32 + ej;
      float ig = glds[0][ej][ec] + (float)gp[0];
      float fg = glds[1][ej][ec] + (float)gp[512];
      float gg = glds[2][ej][ec] + (float)gp[1024];
      float og = glds[3][ej][ec] + (float)gp[1536];
      ig = sigmoidf_(ig); fg = sigmoidf_(fg); og = sigmoidf_(og); gg = tanhf_(gg);
      cstate = fg * cstate + ig * gg;
      const float hv = og * tanhf_(cstate);
      if (t == len_ec - 1) final_h[(size_t)b_ec * D_ + r * 32 + ej] = hv;

      // pack 2 halves per uint, agent-scope store into double-buffered slab
      unsigned hb = (unsigned)(unsigned short)__builtin_bit_cast(unsigned short, (f16)hv);
      unsigned other = __shfl_xor(hb, 1);
      if (!(ej & 1)) {
        unsigned packed = hb | (other << 16);
        const int buf = t & 1;
        __hip_atomic_store(&hGu[(size_t)buf * 4096 * 4 + cl * 4096 + ec * 256 + r * 16 + (ej >> 1)],
                           packed, __ATOMIC_RELAXED, __HIP_MEMORY_SCOPE_AGENT);
      }
    }
    __syncthreads();  // drains all waves' slab stores (vmcnt 0 at barrier)

    // 4. cluster sync: monotonic counter
    if (tid == 0) {
      __hip_atomic_fetch_add(flag, 1u, __ATOMIC_RELEASE, __HIP_MEMORY_SCOPE_AGENT);
      const unsigned target = (unsigned)(t + 1) * 16u;
      while (__hip_atomic_load(flag, __ATOMIC_ACQUIRE, __HIP_MEMORY_SCOPE_AGENT) < target) {
        __builtin_amdgcn_s_sleep(1);
      }
    }
    __syncthreads();

    // 5. gather full h for this cluster -> LDS (agent-scope loads, cur buffer)
    {
      const int buf = t & 1;
      const size_t base = (size_t)buf * 4096 * 4 + cl * 4096 + tid * 8;
      unsigned v[8];
      #pragma unroll
      for (int e = 0; e < 8; ++e)
        v[e] = __hip_atomic_load(&hGu[base + e], __ATOMIC_RELAXED, __HIP_MEMORY_SCOPE_AGENT);
      const int c = tid >> 5, k0 = (tid & 31) * 16;
      unsigned* dst = (unsigned*)&h_lds[c][k0];
      #pragma unroll
      for (int e = 0; e < 8; ++e) dst[e] = v[e];
    }
    __syncthreads();
  }
}

// ---------------- K4: out = final_h @ w_out^T + b_out ----------------
__global__ void k_head(const float* __restrict__ fh, const float* __restrict__ wout,
                       const float* __restrict__ bout, float* __restrict__ out) {
  const int b = blockIdx.x;
  const int lane = threadIdx.x;  // 64
  float p0 = 0.f, p1 = 0.f;
  for (int k = lane; k < D_; k += 64) {
    const float h = fh[(size_t)b * D_ + k];
    p0 += h * wout[k];
    p1 += h * wout[D_ + k];
  }
  #pragma unroll
  for (int off = 32; off; off >>= 1) {
    p0 += __shfl_down(p0, off);
    p1 += __shfl_down(p1, off);
  }
  if (lane == 0) {
    out[b * 2 + 0] = p0 + bout[0];
    out[b * 2 + 1] = p1 + bout[1];
  }
}

extern "C" void kernel_launch(void* const* d_in, const int* in_sizes, int n_in,
                              void* d_out, int out_size, void* d_ws, size_t ws_size,
                              hipStream_t stream) {
  const int* seqs = (const int*)d_in[0];
  const int* lengths = (const int*)d_in[1];
  const float* table = (const float*)d_in[2];
  const float* wih = (const float*)d_in[3];
  const float* whh = (const float*)d_in[4];
  const float* wout = (const float*)d_in[5];
  const float* bout = (const float*)d_in[6];
  float* out = (float*)d_out;
  char* ws = (char*)d_ws;
  if (ws_size < WS_NEED) return;  // workspace too small; bench will flag it

  f16* x = (f16*)(ws + OFF_X);
  f16* G = (f16*)(ws + OFF_G);
  f16* wi16 = (f16*)(ws + OFF_WI);
  unsigned* hGu = (unsigned*)(ws + OFF_HG);
  float* fh = (float*)(ws + OFF_FH);
  unsigned* flags = (unsigned*)(ws + OFF_FL);

  hipLaunchKernelGGL(k_zero, dim3(1), dim3(256), 0, stream, flags);
  hipLaunchKernelGGL(k_embed, dim3(M_), dim3(128), 0, stream, seqs, table, x);
  hipLaunchKernelGGL(k_cvtw, dim3((NG_ * D_ + 255) / 256), dim3(256), 0, stream,
                     wih, wi16, NG_ * D_);
  hipLaunchKernelGGL(k_gemm_ih, dim3(M_ / 64, NG_ / 64), dim3(256), 0, stream, x, wi16, G);
  hipLaunchKernelGGL(k_lstm, dim3(64), dim3(512), 0, stream, whh, G, lengths, hGu, flags, fh);
  hipLaunchKernelGGL(k_head, dim3(B_), dim3(64), 0, stream, fh, wout, bout, out);
}